// Round 6
// baseline (64.903 us; speedup 1.0000x reference)
//
#include <hip/hip_runtime.h>

// Analytic collapse of the "quantum conv" model (PASSED R5, absmax 0.0):
//   <Z_w> = prod_{j<=w} cos(x_j)  (RZ patch_params cancel in |amp|^2)
//   out[b] = sigmoid(cos( sum_p sum_w feats[b,4p+w] * W[4p+w] ))
//   per-patch Horner: c0*(W0 + c1*(W1 + c2*(W2 + c3*W3))).
// Patch p=(gi,gj), 14x14 grid of 2x2 patches, pixels row-major:
//   offsets base, base+1, base+28, base+29, base = 56*gi + 2*gj (base even).
// Dtypes: x f32 [B,784], cp f32 [785], out f32 [B].
//
// R6 delta vs R5: vectorized loads. Patch row-pairs are contiguous ->
// float2 (8B-aligned since base is even); weights W[4p..4p+3] -> float4
// (16B-aligned). 32 scalar VMEM ops/lane -> 12 wide ones, halving the
// latency exposures of this latency-bound tiny kernel.

#define NPATCH 196
#define IMG    784

__global__ __launch_bounds__(256) void fraud_kernel(
    const float* __restrict__ x,      // [B, 784] f32
    const float* __restrict__ cp,     // [785]    f32
    float* __restrict__ out,          // [B] f32
    int B)
{
    const int wave = threadIdx.x >> 6;
    const int lane = threadIdx.x & 63;
    const int waveStride = gridDim.x * 4;

    for (int b = blockIdx.x * 4 + wave; b < B; b += waveStride) {
        const float* xb = x + (size_t)b * IMG;

        float acc = 0.f;
        #pragma unroll
        for (int it = 0; it < 4; ++it) {
            const int p = it * 64 + lane;          // patch index
            if (p < NPATCH) {
                const int gi = p / 14;
                const int gj = p - gi * 14;
                const int base = gi * 56 + gj * 2;                 // even -> 8B aligned
                const float2 r0 = *(const float2*)(xb + base);      // top row pair
                const float2 r1 = *(const float2*)(xb + base + 28); // bottom row pair
                const float4 w  = *(const float4*)(cp + 4 * p);     // 16B aligned
                const float c0 = __cosf(r0.x);
                const float c1 = __cosf(r0.y);
                const float c2 = __cosf(r1.x);
                const float c3 = __cosf(r1.y);
                acc += c0 * fmaf(c1, fmaf(c2, fmaf(c3, w.w, w.z), w.y), w.x);
            }
        }

        // wave64 reduction to lane 0
        #pragma unroll
        for (int off = 32; off > 0; off >>= 1)
            acc += __shfl_down(acc, off, 64);

        if (lane == 0) {
            const float c = cosf(acc);             // |acc| up to ~60: full range reduction
            out[b] = 1.f / (1.f + __expf(-c));     // sigmoid, f32
        }
    }
}

extern "C" void kernel_launch(void* const* d_in, const int* in_sizes, int n_in,
                              void* d_out, int out_size, void* d_ws, size_t ws_size,
                              hipStream_t stream) {
    const float* x  = (const float*)d_in[0];   // [B,1,28,28] f32
    // d_in[1] = patch_params: provably unused (RZ phases cancel in |amp|^2)
    const float* cp = (const float*)d_in[2];   // [785] f32
    float* out = (float*)d_out;                // f32 [B]

    const int B = out_size;                    // batch (4096)
    int blocks = (B + 3) / 4;                  // 4 waves per 256-thread block
    if (blocks > 4096) blocks = 4096;
    if (blocks < 1) blocks = 1;
    fraud_kernel<<<blocks, 256, 0, stream>>>(x, cp, out, B);
}

// Round 7
// 63.764 us; speedup vs baseline: 1.0179x; 1.0179x over previous
//
#include <hip/hip_runtime.h>

// Analytic collapse of the "quantum conv" model (PASSED R5/R6, absmax 0.0):
//   <Z_w> = prod_{j<=w} cos(x_j)  (RZ patch_params cancel in |amp|^2)
//   out[b] = sigmoid(cos( sum_p sum_w feats[b,4p+w] * W[4p+w] ))
//   per-patch Horner: c0*(W0 + c1*(W1 + c2*(W2 + c3*W3))).
// Patch p=(gi,gj), 14x14 grid of 2x2 patches, pixels row-major:
//   offsets base, base+1, base+28, base+29, base = 56*gi + 2*gj (base even).
// Dtypes: x f32 [B,784], cp f32 [785], out f32 [B].
//
// R7 delta vs R6: block-per-batch. 4096 blocks x 256 threads, one patch per
// thread (196 active), wave-reduce + 4-slot LDS combine. 4x wave count for
// latency hiding, 4x less serial work per lane, fully contiguous per-block
// row reads. Discriminating probe: if dur_us doesn't move, the timed window
// is dominated by the harness's 41 us ws-poison fill -> roofline.

#define NPATCH 196
#define IMG    784

__global__ __launch_bounds__(256) void fraud_kernel(
    const float* __restrict__ x,      // [B, 784] f32
    const float* __restrict__ cp,     // [785]    f32
    float* __restrict__ out,          // [B] f32
    int B)
{
    __shared__ float partial[4];
    const int t    = threadIdx.x;
    const int lane = t & 63;
    const int wave = t >> 6;

    for (int b = blockIdx.x; b < B; b += gridDim.x) {
        const float* xb = x + (size_t)b * IMG;

        float acc = 0.f;
        if (t < NPATCH) {
            const int gi = t / 14;
            const int gj = t - gi * 14;
            const int base = gi * 56 + gj * 2;                  // even -> 8B aligned
            const float2 r0 = *(const float2*)(xb + base);      // top row pair
            const float2 r1 = *(const float2*)(xb + base + 28); // bottom row pair
            const float4 w  = *(const float4*)(cp + 4 * t);     // 16B aligned
            acc = __cosf(r0.x) *
                  fmaf(__cosf(r0.y),
                       fmaf(__cosf(r1.x),
                            fmaf(__cosf(r1.y), w.w, w.z), w.y), w.x);
        }

        // wave64 reduction to lane 0
        #pragma unroll
        for (int off = 32; off > 0; off >>= 1)
            acc += __shfl_down(acc, off, 64);

        if (lane == 0) partial[wave] = acc;
        __syncthreads();

        if (t == 0) {
            const float s = partial[0] + partial[1] + partial[2] + partial[3];
            const float c = cosf(s);               // |s| up to ~60: full range reduction
            out[b] = 1.f / (1.f + __expf(-c));     // sigmoid, f32
        }
        __syncthreads();   // protect partial[] if grid-stride loops (B > gridDim.x)
    }
}

extern "C" void kernel_launch(void* const* d_in, const int* in_sizes, int n_in,
                              void* d_out, int out_size, void* d_ws, size_t ws_size,
                              hipStream_t stream) {
    const float* x  = (const float*)d_in[0];   // [B,1,28,28] f32
    // d_in[1] = patch_params: provably unused (RZ phases cancel in |amp|^2)
    const float* cp = (const float*)d_in[2];   // [785] f32
    float* out = (float*)d_out;                // f32 [B]

    const int B = out_size;                    // batch (4096)
    int blocks = B;                            // one block per batch element
    if (blocks > 8192) blocks = 8192;          // grid-stride covers the rest
    if (blocks < 1) blocks = 1;
    fraud_kernel<<<blocks, 256, 0, stream>>>(x, cp, out, B);
}